// Round 21
// baseline (171.893 us; speedup 1.0000x reference)
//
#include <hip/hip_runtime.h>
#include <cstdint>
#include <cstddef>

// ---------------------------------------------------------------------------
// MHA block: out = proj( causal_softmax( (xWq)(xWk)^T / 8 ) (xWv) )
// B=4, T=2048, C=1024, H=16, D=64.  All GEMM-shaped compute on bf16 MFMA.
// ---------------------------------------------------------------------------

typedef short bf16x8 __attribute__((ext_vector_type(8)));
typedef float f32x4 __attribute__((ext_vector_type(4)));
typedef float f32x16 __attribute__((ext_vector_type(16)));

#define MFMA32(a, b, c) __builtin_amdgcn_mfma_f32_16x16x32_bf16((a), (b), (c), 0, 0, 0)
#define MFMA3216(a, b, c) __builtin_amdgcn_mfma_f32_32x32x16_bf16((a), (b), (c), 0, 0, 0)

__device__ __forceinline__ unsigned short f2b(float f) {
  unsigned int x = __builtin_bit_cast(unsigned int, f);
  x += 0x7fffu + ((x >> 16) & 1u);
  return (unsigned short)(x >> 16);
}

__device__ __forceinline__ unsigned int pack2(float a, float b) {
  return (unsigned int)f2b(a) | ((unsigned int)f2b(b) << 16);
}

__device__ __forceinline__ unsigned int cvtpk(float a, float b) {
  unsigned int r;
  asm("v_cvt_pk_bf16_f32 %0, %1, %2" : "=v"(r) : "v"(a), "v"(b));
  return r;
}

__device__ __forceinline__ float exp2v(float x) {
  float r;
  asm("v_exp_f32 %0, %1" : "=v"(r) : "v"(x));
  return r;
}

__device__ __forceinline__ void gload16(const void* g, void* l) {
  __builtin_amdgcn_global_load_lds(
      (const __attribute__((address_space(1))) void*)g,
      (__attribute__((address_space(3))) void*)l, 16, 0, 0);
}

// ---------------------------------------------------------------------------
// Fused prep: one dispatch does x->bf16 convert AND both weight transposes.
//   blocks [0, 8192)      : conv x (f32 -> bf16)
//   blocks [8192, 11264)  : transpose Wqkv -> bf16 3072x1024
//   blocks [11264, 12288) : transpose Wproj -> bf16 1024x1024
// ---------------------------------------------------------------------------
__global__ __launch_bounds__(256) void k_prep(const float* __restrict__ x,
                                              unsigned short* __restrict__ x_bf,
                                              const float* __restrict__ Wqkv,
                                              unsigned short* __restrict__ wqkvT,
                                              const float* __restrict__ Wproj,
                                              unsigned short* __restrict__ wprojT) {
  const int bid = blockIdx.x;
  if (bid < 8192) {
    int i = bid * 256 + threadIdx.x;
    float4 v = reinterpret_cast<const float4*>(x)[i];
    ushort4 o;
    o.x = f2b(v.x); o.y = f2b(v.y); o.z = f2b(v.z); o.w = f2b(v.w);
    reinterpret_cast<ushort4*>(x_bf)[i] = o;
    return;
  }
  __shared__ float tile[32][33];
  const float* in;
  unsigned short* out;
  int R, C, c0, r0;
  if (bid < 11264) {
    int r = bid - 8192;
    in = Wqkv; out = wqkvT; R = 1024; C = 3072;
    c0 = (r % 96) * 32; r0 = (r / 96) * 32;
  } else {
    int r = bid - 11264;
    in = Wproj; out = wprojT; R = 1024; C = 1024;
    c0 = (r % 32) * 32; r0 = (r / 32) * 32;
  }
  int tx = threadIdx.x & 31, ty = threadIdx.x >> 5;
#pragma unroll
  for (int j = 0; j < 4; ++j)
    tile[ty + 8 * j][tx] = in[(size_t)(r0 + ty + 8 * j) * C + c0 + tx];
  __syncthreads();
#pragma unroll
  for (int j = 0; j < 4; ++j)
    out[(size_t)(c0 + ty + 8 * j) * R + r0 + tx] = f2b(tile[tx][ty + 8 * j]);
}

// ---------------------------------------------------------------------------
// bf16 GEMM (exact R17: m97 mainloop + both-sides LDS XOR-swizzle, BK=64,
// launch_bounds(256,5) -> 5 blocks/CU).  128x128 tile, 4 waves, 64x64/wave.
// EPI=0: LDS-bounce epilogue -> q/k/v ws.  EPI=1: direct f32 out.
// ---------------------------------------------------------------------------
template <int EPI>
__global__ __launch_bounds__(256, 5) void k_gemm(const unsigned short* __restrict__ A,
                                                 const unsigned short* __restrict__ Bt,
                                                 float* __restrict__ outF,
                                                 unsigned short* __restrict__ q_ws,
                                                 unsigned short* __restrict__ k_ws,
                                                 unsigned short* __restrict__ v_ws,
                                                 int M, int N) {
  constexpr int K = 1024;
  __shared__ unsigned short smem[16384];  // As | Bs; epilogue reuses
  unsigned short* As = smem;
  unsigned short* Bs = smem + 8192;
  const int bn = blockIdx.x, bm = blockIdx.y;
  const int tid = threadIdx.x;
  const int w = tid >> 6, lane = tid & 63;
  const int wm = w >> 1, wn = w & 1;
  const int c = lane & 15, g = lane >> 4;
  const int cl8 = c & 7;

  f32x4 acc[4][4];
#pragma unroll
  for (int i = 0; i < 4; ++i)
#pragma unroll
    for (int j = 0; j < 4; ++j) acc[i][j] = (f32x4){0.f, 0.f, 0.f, 0.f};

  const int srow = 32 * w + (lane >> 3);
  const int scol = 8 * ((lane & 7) ^ (lane >> 3));
  const unsigned short* Ag = A + (size_t)(bm * 128 + srow) * K + scol;
  const unsigned short* Bg = Bt + (size_t)(bn * 128 + srow) * K + scol;
  char* AsB = (char*)As + w * 4096;
  char* BsB = (char*)Bs + w * 4096;

  for (int kt = 0; kt < K / 64; ++kt) {
    const int kb = kt * 64;
    __syncthreads();
#pragma unroll
    for (int i = 0; i < 4; ++i) {
      gload16(Ag + (size_t)(8 * i) * K + kb, AsB + i * 1024);
      gload16(Bg + (size_t)(8 * i) * K + kb, BsB + i * 1024);
    }
    asm volatile("s_waitcnt vmcnt(0)" ::: "memory");
    __syncthreads();
#pragma unroll
    for (int u = 0; u < 2; ++u) {
      bf16x8 af[4], bfr[4];
#pragma unroll
      for (int mf = 0; mf < 4; ++mf)
        af[mf] = *(const bf16x8*)((const char*)As + (wm * 64 + mf * 16 + c) * 128 +
                                  (((u * 4 + g) ^ cl8) * 16));
#pragma unroll
      for (int nf = 0; nf < 4; ++nf)
        bfr[nf] = *(const bf16x8*)((const char*)Bs + (wn * 64 + nf * 16 + c) * 128 +
                                   (((u * 4 + g) ^ cl8) * 16));
#pragma unroll
      for (int mf = 0; mf < 4; ++mf)
#pragma unroll
        for (int nf = 0; nf < 4; ++nf)
          acc[mf][nf] = MFMA32(af[mf], bfr[nf], acc[mf][nf]);
    }
  }

  const int rowb = bm * 128 + wm * 64;
  const int colb = bn * 128 + wn * 64;
  if (EPI == 1) {
#pragma unroll
    for (int mf = 0; mf < 4; ++mf)
#pragma unroll
      for (int nf = 0; nf < 4; ++nf)
#pragma unroll
        for (int r = 0; r < 4; ++r) {
          int row = rowb + mf * 16 + 4 * g + r;
          int col = colb + nf * 16 + c;
          outF[(size_t)row * N + col] = acc[mf][nf][r];
        }
  } else {
    const int sec = colb >> 10;
    const int hh = (colb & 1023) >> 6;
    const int b = rowb >> 11, t0 = rowb & 2047;
    unsigned short* Lw = smem + w * 4096;

    __syncthreads();
    if (sec < 2) {
      const float sc = (sec == 0) ? 0.125f * 1.4426950408889634f : 1.f;
#pragma unroll
      for (int mf = 0; mf < 4; ++mf)
#pragma unroll
        for (int nf = 0; nf < 4; ++nf)
#pragma unroll
          for (int r = 0; r < 4; ++r)
            Lw[(16 * mf + 4 * g + r) * 64 + 16 * nf + c] = f2b(acc[mf][nf][r] * sc);
    } else {
#pragma unroll
      for (int mf = 0; mf < 4; ++mf)
#pragma unroll
        for (int nf = 0; nf < 4; ++nf)
#pragma unroll
          for (int rr = 0; rr < 2; ++rr)
            *(unsigned int*)&Lw[(16 * nf + c) * 64 + 16 * mf + 4 * g + 2 * rr] =
                pack2(acc[mf][nf][2 * rr], acc[mf][nf][2 * rr + 1]);
    }
    asm volatile("s_waitcnt lgkmcnt(0)" ::: "memory");
    const int rw = lane >> 3, ch = lane & 7;
    const int chx = ch ^ rw;
    if (sec == 0) {
      unsigned short* dst = q_ws + ((size_t)(b * 16 + hh) * 2048 + t0) * 64;
#pragma unroll
      for (int i = 0; i < 8; ++i) {
        int tl = i * 8 + rw;
        *(bf16x8*)(dst + (size_t)tl * 64 + ch * 8) = *(const bf16x8*)&Lw[tl * 64 + ch * 8];
      }
    } else if (sec == 1) {
      unsigned short* dst = k_ws + ((size_t)(b * 16 + hh) * 2048 + t0) * 64;
#pragma unroll
      for (int i = 0; i < 8; ++i) {
        int tl = i * 8 + rw;
        *(bf16x8*)(dst + (size_t)tl * 64 + chx * 8) = *(const bf16x8*)&Lw[tl * 64 + ch * 8];
      }
    } else {
      unsigned short* dst = v_ws + (size_t)(b * 16 + hh) * 64 * 2048 + t0;
#pragma unroll
      for (int i = 0; i < 8; ++i) {
        int dl = i * 8 + rw;
        *(bf16x8*)(dst + (size_t)dl * 2048 + chx * 8) = *(const bf16x8*)&Lw[dl * 64 + ch * 8];
      }
    }
  }
}

// ---------------------------------------------------------------------------
// Flash attention, causal.  R18 32x32x16 compute, NEW (R21) 8-wave blocks:
// 512 blocks x 512 thr, ONE 256-row q-tile per block (wave w owns rows
// 32w..32w+31) -> 2 blocks/CU = 16 waves/CU (same as R18) but per-wave
// staging halves (2 gload16/kt, vmcnt(2)) and per-CU LDS-write traffic
// halves.  8 length classes (n_kt = 4xi+4 in {4..32}), longest-first ->
// greedy pairs 32+4, 28+8, 24+12, 20+16 = exactly 36 kt per CU.
// 8 bh planes per XCD chunk (L2-fit).
// ---------------------------------------------------------------------------
__global__ __launch_bounds__(512, 2) void k_attn(const unsigned short* __restrict__ q_ws,
                                                 const unsigned short* __restrict__ k_ws,
                                                 const unsigned short* __restrict__ v_ws,
                                                 unsigned short* __restrict__ y_ws) {
  constexpr int T = 2048;
  __shared__ unsigned short Ks[2][64 * 64];
  __shared__ unsigned short Vs[2][64 * 64];
  // f&7 -> XCD chunk; r = f>>3 in [0,64): bh = chunk*8 + (r&7), xi = 7-(r>>3)
  const int f = blockIdx.x;
  const int r = f >> 3;
  const int bh = (f & 7) * 8 + (r & 7);
  const int xi = 7 - (r >> 3);
  const int tid = threadIdx.x, w = tid >> 6, lane = tid & 63;
  const int q32 = lane & 31;
  const int hi = lane >> 5;
  const int l7 = lane & 7;
  const size_t base = (size_t)bh * T * 64;
  const unsigned short* Kb = k_ws + base;
  const unsigned short* Vb = v_ws + base;
  const unsigned short* Qb = q_ws + base;

  // staging: wave w covers 8 rows of K and 8 of V per kt (1 gload16 each)
  const int srow = w * 8 + (lane >> 3);
  const int sch = lane & 7;

  const int q0 = xi * 256;
  const int qb = q0 + 32 * w;
  const int qcol = qb + q32;
  const int n_kt = (q0 >> 6) + 4;  // = 4*xi + 4
  bf16x8 qf[4];
#pragma unroll
  for (int ks = 0; ks < 4; ++ks)
    qf[ks] = *(const bf16x8*)(Qb + (size_t)qcol * 64 + 16 * ks + 8 * hi);

  f32x16 yacc[2];
#pragma unroll
  for (int db = 0; db < 2; ++db)
#pragma unroll
    for (int i = 0; i < 16; ++i) yacc[db][i] = 0.f;
  float m_run = -1e30f, l_part = 0.f;

  // prologue: stage kt=0 into buf 0 (1 K + 1 V gload16 per wave)
  gload16(Kb + (size_t)srow * 64 + sch * 8, (char*)&Ks[0][0] + w * 1024);
  gload16(Vb + (size_t)srow * T + sch * 8, (char*)&Vs[0][0] + w * 1024);

#pragma unroll 1
  for (int kt = 0; kt < n_kt; ++kt) {
    const int k0 = kt * 64;
    const int cur = kt & 1;
    if (kt + 1 < n_kt) {
      const int k0n = k0 + 64;
      gload16(Kb + (size_t)(k0n + srow) * 64 + sch * 8, (char*)&Ks[cur ^ 1][0] + w * 1024);
      gload16(Vb + (size_t)srow * T + k0n + sch * 8, (char*)&Vs[cur ^ 1][0] + w * 1024);
      asm volatile("s_waitcnt vmcnt(2)" ::: "memory");
    } else {
      asm volatile("s_waitcnt vmcnt(0)" ::: "memory");
    }
    __builtin_amdgcn_s_barrier();

    if (k0 <= qb + 31) {  // wave-uniform causal gate
      const char* KsC = (const char*)&Ks[cur][0];
      const char* VsC = (const char*)&Vs[cur][0];
      f32x16 s[2];
#pragma unroll
      for (int tb = 0; tb < 2; ++tb)
#pragma unroll
        for (int i = 0; i < 16; ++i) s[tb][i] = 0.f;
      __builtin_amdgcn_s_setprio(1);
#pragma unroll
      for (int ks = 0; ks < 4; ++ks) {
        const int chk = ((2 * ks + hi) ^ l7) * 16;
#pragma unroll
        for (int tb = 0; tb < 2; ++tb) {
          const int row = 32 * tb + q32;
          bf16x8 kf = *(const bf16x8*)(KsC + row * 128 + chk);
          s[tb] = MFMA3216(kf, qf[ks], s[tb]);
        }
      }
      __builtin_amdgcn_s_setprio(0);
      if (k0 + 63 > qb) {  // causal mask: tk = k0+32tb+(rr&3)+8*(rr>>2)+4hi
#pragma unroll
        for (int tb = 0; tb < 2; ++tb)
#pragma unroll
          for (int rr = 0; rr < 16; ++rr) {
            int tk = k0 + 32 * tb + (rr & 3) + 8 * (rr >> 2) + 4 * hi;
            if (tk > qcol) s[tb][rr] = -1e30f;
          }
      }
      float mx = s[0][0];
#pragma unroll
      for (int tb = 0; tb < 2; ++tb)
#pragma unroll
        for (int rr = 0; rr < 16; ++rr) mx = fmaxf(mx, s[tb][rr]);
      mx = fmaxf(mx, __shfl_xor(mx, 32));
      if (__any(mx > m_run + 11.5f)) {
        float m_new = fmaxf(m_run, mx);
        float corr = exp2v(m_run - m_new);
        l_part *= corr;
#pragma unroll
        for (int db = 0; db < 2; ++db)
#pragma unroll
          for (int i = 0; i < 16; ++i) yacc[db][i] *= corr;
        m_run = m_new;
      }
      unsigned pk[2][8];
      float ps = 0.f;
#pragma unroll
      for (int tb = 0; tb < 2; ++tb)
#pragma unroll
        for (int q4 = 0; q4 < 4; ++q4) {
          float p0 = exp2v(s[tb][4 * q4 + 0] - m_run);
          float p1 = exp2v(s[tb][4 * q4 + 1] - m_run);
          float p2 = exp2v(s[tb][4 * q4 + 2] - m_run);
          float p3 = exp2v(s[tb][4 * q4 + 3] - m_run);
          ps += ((p0 + p1) + (p2 + p3));
          pk[tb][2 * q4] = cvtpk(p0, p1);
          pk[tb][2 * q4 + 1] = cvtpk(p2, p3);
        }
      l_part += ps;

#pragma unroll
      for (int kw = 0; kw < 4; ++kw) {
        const int tb = kw >> 1, a = kw & 1;
        unsigned g00 = pk[tb][4 * a + 0], g01 = pk[tb][4 * a + 1];
        unsigned g10 = pk[tb][4 * a + 2], g11 = pk[tb][4 * a + 3];
        unsigned own0 = hi ? g10 : g00, own1 = hi ? g11 : g01;
        unsigned snd0 = hi ? g00 : g10, snd1 = hi ? g01 : g11;
        unsigned X0 = __shfl_xor(snd0, 32), X1 = __shfl_xor(snd1, 32);
        union { unsigned int u[4]; bf16x8 v; } pb;
        pb.u[0] = hi ? X0 : own0;
        pb.u[1] = hi ? X1 : own1;
        pb.u[2] = hi ? own0 : X0;
        pb.u[3] = hi ? own1 : X1;
        const int chv = ((2 * kw + hi) ^ l7) * 16;
        __builtin_amdgcn_s_setprio(1);
#pragma unroll
        for (int db = 0; db < 2; ++db) {
          const int row = 32 * db + q32;
          bf16x8 vf = *(const bf16x8*)(VsC + row * 128 + chv);
          yacc[db] = MFMA3216(vf, pb.v, yacc[db]);
        }
        __builtin_amdgcn_s_setprio(0);
      }
    }
    __builtin_amdgcn_s_barrier();
  }

  float lt = l_part + __shfl_xor(l_part, 32);
  float inv = 1.f / lt;
  const int b = bh >> 4, hh = bh & 15;
  unsigned short* yrow = y_ws + (size_t)(b * 2048 + qcol) * 1024 + hh * 64;
#pragma unroll
  for (int db = 0; db < 2; ++db)
#pragma unroll
    for (int rg = 0; rg < 4; ++rg) {
      uint2 o;
      o.x = cvtpk(yacc[db][4 * rg + 0] * inv, yacc[db][4 * rg + 1] * inv);
      o.y = cvtpk(yacc[db][4 * rg + 2] * inv, yacc[db][4 * rg + 3] * inv);
      *(uint2*)(yrow + 32 * db + 8 * rg + 4 * hi) = o;
    }
}

// ---------------------------------------------------------------------------
extern "C" void kernel_launch(void* const* d_in, const int* in_sizes, int n_in,
                              void* d_out, int out_size, void* d_ws, size_t ws_size,
                              hipStream_t stream) {
  const float* x = (const float*)d_in[0];      // (4, 2048, 1024)
  const float* Wqkv = (const float*)d_in[1];   // (1024, 3072)
  const float* Wproj = (const float*)d_in[2];  // (1024, 1024)
  float* out = (float*)d_out;                  // (4, 2048, 1024)
  char* ws = (char*)d_ws;

  unsigned short* x_bf = (unsigned short*)(ws);                    // 16 MiB
  unsigned short* wqkvT = (unsigned short*)(ws + 16777216);        // 6 MiB
  unsigned short* wprojT = (unsigned short*)(ws + 23068672);       // 2 MiB
  unsigned short* q_ws = (unsigned short*)(ws + 25165824);         // 16 MiB
  unsigned short* k_ws = (unsigned short*)(ws + 41943040);         // 16 MiB
  unsigned short* v_ws = (unsigned short*)(ws + 58720256);         // 16 MiB
  unsigned short* y_ws = (unsigned short*)(ws + 75497472);         // 16 MiB

  k_prep<<<12288, 256, 0, stream>>>(x, x_bf, Wqkv, wqkvT, Wproj, wprojT);
  k_gemm<0><<<dim3(24, 64), 256, 0, stream>>>(x_bf, wqkvT, nullptr, q_ws, k_ws, v_ws, 8192, 3072);
  k_attn<<<512, 512, 0, stream>>>(q_ws, k_ws, v_ws, y_ws);
  k_gemm<1><<<dim3(8, 64), 256, 0, stream>>>(y_ws, wprojT, out, nullptr, nullptr, nullptr, 8192, 1024);
}

// Round 23
// 167.192 us; speedup vs baseline: 1.0281x; 1.0281x over previous
//
#include <hip/hip_runtime.h>
#include <cstdint>
#include <cstddef>

// ---------------------------------------------------------------------------
// MHA block: out = proj( causal_softmax( (xWq)(xWk)^T / 8 ) (xWv) )
// B=4, T=2048, C=1024, H=16, D=64.  All GEMM-shaped compute on bf16 MFMA.
// R23 = R20 config + race hardening: every raw s_barrier in k_attn is
// followed by sched_barrier(0) so the compiler cannot hoist LDS reads above
// the barrier or sink staging issues below it (R22 post-timing flake).
// ---------------------------------------------------------------------------

typedef short bf16x8 __attribute__((ext_vector_type(8)));
typedef float f32x4 __attribute__((ext_vector_type(4)));
typedef float f32x16 __attribute__((ext_vector_type(16)));

#define MFMA32(a, b, c) __builtin_amdgcn_mfma_f32_16x16x32_bf16((a), (b), (c), 0, 0, 0)
#define MFMA3216(a, b, c) __builtin_amdgcn_mfma_f32_32x32x16_bf16((a), (b), (c), 0, 0, 0)

__device__ __forceinline__ unsigned short f2b(float f) {
  unsigned int x = __builtin_bit_cast(unsigned int, f);
  x += 0x7fffu + ((x >> 16) & 1u);
  return (unsigned short)(x >> 16);
}

__device__ __forceinline__ unsigned int pack2(float a, float b) {
  return (unsigned int)f2b(a) | ((unsigned int)f2b(b) << 16);
}

__device__ __forceinline__ unsigned int cvtpk(float a, float b) {
  unsigned int r;
  asm("v_cvt_pk_bf16_f32 %0, %1, %2" : "=v"(r) : "v"(a), "v"(b));
  return r;
}

__device__ __forceinline__ float exp2v(float x) {
  float r;
  asm("v_exp_f32 %0, %1" : "=v"(r) : "v"(x));
  return r;
}

__device__ __forceinline__ void gload16(const void* g, void* l) {
  __builtin_amdgcn_global_load_lds(
      (const __attribute__((address_space(1))) void*)g,
      (__attribute__((address_space(3))) void*)l, 16, 0, 0);
}

// hardened block barrier: HW barrier + compiler "nothing crosses" fence
__device__ __forceinline__ void hard_barrier() {
  asm volatile("" ::: "memory");
  __builtin_amdgcn_s_barrier();
  __builtin_amdgcn_sched_barrier(0);
}

// ---------------------------------------------------------------------------
// Fused prep: one dispatch does x->bf16 convert AND both weight transposes.
//   blocks [0, 8192)      : conv x (f32 -> bf16)
//   blocks [8192, 11264)  : transpose Wqkv -> bf16 3072x1024
//   blocks [11264, 12288) : transpose Wproj -> bf16 1024x1024
// ---------------------------------------------------------------------------
__global__ __launch_bounds__(256) void k_prep(const float* __restrict__ x,
                                              unsigned short* __restrict__ x_bf,
                                              const float* __restrict__ Wqkv,
                                              unsigned short* __restrict__ wqkvT,
                                              const float* __restrict__ Wproj,
                                              unsigned short* __restrict__ wprojT) {
  const int bid = blockIdx.x;
  if (bid < 8192) {
    int i = bid * 256 + threadIdx.x;
    float4 v = reinterpret_cast<const float4*>(x)[i];
    ushort4 o;
    o.x = f2b(v.x); o.y = f2b(v.y); o.z = f2b(v.z); o.w = f2b(v.w);
    reinterpret_cast<ushort4*>(x_bf)[i] = o;
    return;
  }
  __shared__ float tile[32][33];
  const float* in;
  unsigned short* out;
  int R, C, c0, r0;
  if (bid < 11264) {
    int r = bid - 8192;
    in = Wqkv; out = wqkvT; R = 1024; C = 3072;
    c0 = (r % 96) * 32; r0 = (r / 96) * 32;
  } else {
    int r = bid - 11264;
    in = Wproj; out = wprojT; R = 1024; C = 1024;
    c0 = (r % 32) * 32; r0 = (r / 32) * 32;
  }
  int tx = threadIdx.x & 31, ty = threadIdx.x >> 5;
#pragma unroll
  for (int j = 0; j < 4; ++j)
    tile[ty + 8 * j][tx] = in[(size_t)(r0 + ty + 8 * j) * C + c0 + tx];
  __syncthreads();
#pragma unroll
  for (int j = 0; j < 4; ++j)
    out[(size_t)(c0 + ty + 8 * j) * R + r0 + tx] = f2b(tile[tx][ty + 8 * j]);
}

// ---------------------------------------------------------------------------
// bf16 GEMM (m97 mainloop + both-sides LDS XOR-swizzle, BK=64,
// launch_bounds(256,5) -> 5 blocks/CU).  128x128 tile, 4 waves, 64x64/wave.
// Uses __syncthreads() (full drain) -> no raw-barrier race surface.
// EPI=0: LDS-bounce epilogue -> q/k/v ws.  EPI=1: direct f32 out.
// ---------------------------------------------------------------------------
template <int EPI>
__global__ __launch_bounds__(256, 5) void k_gemm(const unsigned short* __restrict__ A,
                                                 const unsigned short* __restrict__ Bt,
                                                 float* __restrict__ outF,
                                                 unsigned short* __restrict__ q_ws,
                                                 unsigned short* __restrict__ k_ws,
                                                 unsigned short* __restrict__ v_ws,
                                                 int M, int N) {
  constexpr int K = 1024;
  __shared__ unsigned short smem[16384];  // As | Bs; epilogue reuses
  unsigned short* As = smem;
  unsigned short* Bs = smem + 8192;
  const int bn = blockIdx.x, bm = blockIdx.y;
  const int tid = threadIdx.x;
  const int w = tid >> 6, lane = tid & 63;
  const int wm = w >> 1, wn = w & 1;
  const int c = lane & 15, g = lane >> 4;
  const int cl8 = c & 7;

  f32x4 acc[4][4];
#pragma unroll
  for (int i = 0; i < 4; ++i)
#pragma unroll
    for (int j = 0; j < 4; ++j) acc[i][j] = (f32x4){0.f, 0.f, 0.f, 0.f};

  const int srow = 32 * w + (lane >> 3);
  const int scol = 8 * ((lane & 7) ^ (lane >> 3));
  const unsigned short* Ag = A + (size_t)(bm * 128 + srow) * K + scol;
  const unsigned short* Bg = Bt + (size_t)(bn * 128 + srow) * K + scol;
  char* AsB = (char*)As + w * 4096;
  char* BsB = (char*)Bs + w * 4096;

  for (int kt = 0; kt < K / 64; ++kt) {
    const int kb = kt * 64;
    __syncthreads();
#pragma unroll
    for (int i = 0; i < 4; ++i) {
      gload16(Ag + (size_t)(8 * i) * K + kb, AsB + i * 1024);
      gload16(Bg + (size_t)(8 * i) * K + kb, BsB + i * 1024);
    }
    asm volatile("s_waitcnt vmcnt(0)" ::: "memory");
    __syncthreads();
#pragma unroll
    for (int u = 0; u < 2; ++u) {
      bf16x8 af[4], bfr[4];
#pragma unroll
      for (int mf = 0; mf < 4; ++mf)
        af[mf] = *(const bf16x8*)((const char*)As + (wm * 64 + mf * 16 + c) * 128 +
                                  (((u * 4 + g) ^ cl8) * 16));
#pragma unroll
      for (int nf = 0; nf < 4; ++nf)
        bfr[nf] = *(const bf16x8*)((const char*)Bs + (wn * 64 + nf * 16 + c) * 128 +
                                   (((u * 4 + g) ^ cl8) * 16));
#pragma unroll
      for (int mf = 0; mf < 4; ++mf)
#pragma unroll
        for (int nf = 0; nf < 4; ++nf)
          acc[mf][nf] = MFMA32(af[mf], bfr[nf], acc[mf][nf]);
    }
  }

  const int rowb = bm * 128 + wm * 64;
  const int colb = bn * 128 + wn * 64;
  if (EPI == 1) {
#pragma unroll
    for (int mf = 0; mf < 4; ++mf)
#pragma unroll
      for (int nf = 0; nf < 4; ++nf)
#pragma unroll
        for (int r = 0; r < 4; ++r) {
          int row = rowb + mf * 16 + 4 * g + r;
          int col = colb + nf * 16 + c;
          outF[(size_t)row * N + col] = acc[mf][nf][r];
        }
  } else {
    const int sec = colb >> 10;
    const int hh = (colb & 1023) >> 6;
    const int b = rowb >> 11, t0 = rowb & 2047;
    unsigned short* Lw = smem + w * 4096;

    __syncthreads();
    if (sec < 2) {
      const float sc = (sec == 0) ? 0.125f * 1.4426950408889634f : 1.f;
#pragma unroll
      for (int mf = 0; mf < 4; ++mf)
#pragma unroll
        for (int nf = 0; nf < 4; ++nf)
#pragma unroll
          for (int r = 0; r < 4; ++r)
            Lw[(16 * mf + 4 * g + r) * 64 + 16 * nf + c] = f2b(acc[mf][nf][r] * sc);
    } else {
#pragma unroll
      for (int mf = 0; mf < 4; ++mf)
#pragma unroll
        for (int nf = 0; nf < 4; ++nf)
#pragma unroll
          for (int rr = 0; rr < 2; ++rr)
            *(unsigned int*)&Lw[(16 * nf + c) * 64 + 16 * mf + 4 * g + 2 * rr] =
                pack2(acc[mf][nf][2 * rr], acc[mf][nf][2 * rr + 1]);
    }
    asm volatile("s_waitcnt lgkmcnt(0)" ::: "memory");
    __builtin_amdgcn_sched_barrier(0);
    const int rw = lane >> 3, ch = lane & 7;
    const int chx = ch ^ rw;
    if (sec == 0) {
      unsigned short* dst = q_ws + ((size_t)(b * 16 + hh) * 2048 + t0) * 64;
#pragma unroll
      for (int i = 0; i < 8; ++i) {
        int tl = i * 8 + rw;
        *(bf16x8*)(dst + (size_t)tl * 64 + ch * 8) = *(const bf16x8*)&Lw[tl * 64 + ch * 8];
      }
    } else if (sec == 1) {
      unsigned short* dst = k_ws + ((size_t)(b * 16 + hh) * 2048 + t0) * 64;
#pragma unroll
      for (int i = 0; i < 8; ++i) {
        int tl = i * 8 + rw;
        *(bf16x8*)(dst + (size_t)tl * 64 + chx * 8) = *(const bf16x8*)&Lw[tl * 64 + ch * 8];
      }
    } else {
      unsigned short* dst = v_ws + (size_t)(b * 16 + hh) * 64 * 2048 + t0;
#pragma unroll
      for (int i = 0; i < 8; ++i) {
        int dl = i * 8 + rw;
        *(bf16x8*)(dst + (size_t)dl * 2048 + chx * 8) = *(const bf16x8*)&Lw[dl * 64 + ch * 8];
      }
    }
  }
}

// ---------------------------------------------------------------------------
// Flash attention, causal.  32x32x16 MFMA structure.
// 1024 blocks x 256 thr (4 waves), ONE 128-row q-tile per block, ~4 blocks/CU.
// Longest-first dispatch (xi descending within XCD chunk); 8 bh planes/XCD.
// Wave owns 32 q-rows (col = lane&31); lane-local softmax + 1 shfl_xor(32);
// P->B regroup with 2 shfl_xor(32)/kw; KVBLK=64 dbuf, vmcnt(4),
// HARDENED raw barriers (s_barrier + sched_barrier(0) compiler fence).
// ---------------------------------------------------------------------------
__global__ __launch_bounds__(256, 4) void k_attn(const unsigned short* __restrict__ q_ws,
                                                 const unsigned short* __restrict__ k_ws,
                                                 const unsigned short* __restrict__ v_ws,
                                                 unsigned short* __restrict__ y_ws) {
  constexpr int T = 2048;
  __shared__ unsigned short Ks[2][64 * 64];
  __shared__ unsigned short Vs[2][64 * 64];
  const int f = blockIdx.x;
  const int r = f >> 3;
  const int bh = (f & 7) * 8 + (r & 7);
  const int xi = 15 - (r >> 3);
  const int tid = threadIdx.x, w = tid >> 6, lane = tid & 63;
  const int q32 = lane & 31;
  const int hi = lane >> 5;
  const int l7 = lane & 7;
  const size_t base = (size_t)bh * T * 64;
  const unsigned short* Kb = k_ws + base;
  const unsigned short* Vb = v_ws + base;
  const unsigned short* Qb = q_ws + base;

  const int srow = w * 16 + (lane >> 3);
  const int sch = lane & 7;

  const int q0 = xi * 128;
  const int qb = q0 + 32 * w;
  const int qcol = qb + q32;
  const int n_kt = (q0 >> 6) + 2;
  bf16x8 qf[4];
#pragma unroll
  for (int ks = 0; ks < 4; ++ks)
    qf[ks] = *(const bf16x8*)(Qb + (size_t)qcol * 64 + 16 * ks + 8 * hi);

  f32x16 yacc[2];
#pragma unroll
  for (int db = 0; db < 2; ++db)
#pragma unroll
    for (int i = 0; i < 16; ++i) yacc[db][i] = 0.f;
  float m_run = -1e30f, l_part = 0.f;

  // prologue: stage kt=0 into buf 0
  gload16(Kb + (size_t)srow * 64 + sch * 8, (char*)&Ks[0][0] + w * 2048);
  gload16(Kb + (size_t)(srow + 8) * 64 + sch * 8, (char*)&Ks[0][0] + w * 2048 + 1024);
  gload16(Vb + (size_t)srow * T + sch * 8, (char*)&Vs[0][0] + w * 2048);
  gload16(Vb + (size_t)(srow + 8) * T + sch * 8, (char*)&Vs[0][0] + w * 2048 + 1024);

#pragma unroll 1
  for (int kt = 0; kt < n_kt; ++kt) {
    const int k0 = kt * 64;
    const int cur = kt & 1;
    if (kt + 1 < n_kt) {
      const int k0n = k0 + 64;
      char* KsW = (char*)&Ks[cur ^ 1][0] + w * 2048;
      char* VsW = (char*)&Vs[cur ^ 1][0] + w * 2048;
      gload16(Kb + (size_t)(k0n + srow) * 64 + sch * 8, KsW);
      gload16(Kb + (size_t)(k0n + srow + 8) * 64 + sch * 8, KsW + 1024);
      gload16(Vb + (size_t)srow * T + k0n + sch * 8, VsW);
      gload16(Vb + (size_t)(srow + 8) * T + k0n + sch * 8, VsW + 1024);
      asm volatile("s_waitcnt vmcnt(4)" ::: "memory");
    } else {
      asm volatile("s_waitcnt vmcnt(0)" ::: "memory");
    }
    hard_barrier();  // all waves' pair(kt) staging visible; reads fenced below

    if (k0 <= qb + 31) {  // wave-uniform
      const char* KsC = (const char*)&Ks[cur][0];
      const char* VsC = (const char*)&Vs[cur][0];
      f32x16 s[2];
#pragma unroll
      for (int tb = 0; tb < 2; ++tb)
#pragma unroll
        for (int i = 0; i < 16; ++i) s[tb][i] = 0.f;
      __builtin_amdgcn_s_setprio(1);
#pragma unroll
      for (int ks = 0; ks < 4; ++ks) {
        const int chk = ((2 * ks + hi) ^ l7) * 16;
#pragma unroll
        for (int tb = 0; tb < 2; ++tb) {
          const int row = 32 * tb + q32;
          bf16x8 kf = *(const bf16x8*)(KsC + row * 128 + chk);
          s[tb] = MFMA3216(kf, qf[ks], s[tb]);
        }
      }
      __builtin_amdgcn_s_setprio(0);
      if (k0 + 63 > qb) {  // causal mask: tk = k0+32tb+(rr&3)+8*(rr>>2)+4hi
#pragma unroll
        for (int tb = 0; tb < 2; ++tb)
#pragma unroll
          for (int rr = 0; rr < 16; ++rr) {
            int tk = k0 + 32 * tb + (rr & 3) + 8 * (rr >> 2) + 4 * hi;
            if (tk > qcol) s[tb][rr] = -1e30f;
          }
      }
      float mx = s[0][0];
#pragma unroll
      for (int tb = 0; tb < 2; ++tb)
#pragma unroll
        for (int rr = 0; rr < 16; ++rr) mx = fmaxf(mx, s[tb][rr]);
      mx = fmaxf(mx, __shfl_xor(mx, 32));
      if (__any(mx > m_run + 11.5f)) {
        float m_new = fmaxf(m_run, mx);
        float corr = exp2v(m_run - m_new);
        l_part *= corr;
#pragma unroll
        for (int db = 0; db < 2; ++db)
#pragma unroll
          for (int i = 0; i < 16; ++i) yacc[db][i] *= corr;
        m_run = m_new;
      }
      unsigned pk[2][8];
      float ps = 0.f;
#pragma unroll
      for (int tb = 0; tb < 2; ++tb)
#pragma unroll
        for (int q4 = 0; q4 < 4; ++q4) {
          float p0 = exp2v(s[tb][4 * q4 + 0] - m_run);
          float p1 = exp2v(s[tb][4 * q4 + 1] - m_run);
          float p2 = exp2v(s[tb][4 * q4 + 2] - m_run);
          float p3 = exp2v(s[tb][4 * q4 + 3] - m_run);
          ps += ((p0 + p1) + (p2 + p3));
          pk[tb][2 * q4] = cvtpk(p0, p1);
          pk[tb][2 * q4 + 1] = cvtpk(p2, p3);
        }
      l_part += ps;

#pragma unroll
      for (int kw = 0; kw < 4; ++kw) {
        const int tb = kw >> 1, a = kw & 1;
        unsigned g00 = pk[tb][4 * a + 0], g01 = pk[tb][4 * a + 1];
        unsigned g10 = pk[tb][4 * a + 2], g11 = pk[tb][4 * a + 3];
        unsigned own0 = hi ? g10 : g00, own1 = hi ? g11 : g01;
        unsigned snd0 = hi ? g00 : g10, snd1 = hi ? g01 : g11;
        unsigned X0 = __shfl_xor(snd0, 32), X1 = __shfl_xor(snd1, 32);
        union { unsigned int u[4]; bf16x8 v; } pb;
        pb.u[0] = hi ? X0 : own0;
        pb.u[1] = hi ? X1 : own1;
        pb.u[2] = hi ? own0 : X0;
        pb.u[3] = hi ? own1 : X1;
        const int chv = ((2 * kw + hi) ^ l7) * 16;
        __builtin_amdgcn_s_setprio(1);
#pragma unroll
        for (int db = 0; db < 2; ++db) {
          const int row = 32 * db + q32;
          bf16x8 vf = *(const bf16x8*)(VsC + row * 128 + chv);
          yacc[db] = MFMA3216(vf, pb.v, yacc[db]);
        }
        __builtin_amdgcn_s_setprio(0);
      }
    }
    hard_barrier();  // readers done before next iter's staging overwrites
  }

  float lt = l_part + __shfl_xor(l_part, 32);
  float inv = 1.f / lt;
  const int b = bh >> 4, hh = bh & 15;
  unsigned short* yrow = y_ws + (size_t)(b * 2048 + qcol) * 1024 + hh * 64;
#pragma unroll
  for (int db = 0; db < 2; ++db)
#pragma unroll
    for (int rg = 0; rg < 4; ++rg) {
      uint2 o;
      o.x = cvtpk(yacc[db][4 * rg + 0] * inv, yacc[db][4 * rg + 1] * inv);
      o.y = cvtpk(yacc[db][4 * rg + 2] * inv, yacc[db][4 * rg + 3] * inv);
      *(uint2*)(yrow + 32 * db + 8 * rg + 4 * hi) = o;
    }
}

// ---------------------------------------------------------------------------
extern "C" void kernel_launch(void* const* d_in, const int* in_sizes, int n_in,
                              void* d_out, int out_size, void* d_ws, size_t ws_size,
                              hipStream_t stream) {
  const float* x = (const float*)d_in[0];      // (4, 2048, 1024)
  const float* Wqkv = (const float*)d_in[1];   // (1024, 3072)
  const float* Wproj = (const float*)d_in[2];  // (1024, 1024)
  float* out = (float*)d_out;                  // (4, 2048, 1024)
  char* ws = (char*)d_ws;

  unsigned short* x_bf = (unsigned short*)(ws);                    // 16 MiB
  unsigned short* wqkvT = (unsigned short*)(ws + 16777216);        // 6 MiB
  unsigned short* wprojT = (unsigned short*)(ws + 23068672);       // 2 MiB
  unsigned short* q_ws = (unsigned short*)(ws + 25165824);         // 16 MiB
  unsigned short* k_ws = (unsigned short*)(ws + 41943040);         // 16 MiB
  unsigned short* v_ws = (unsigned short*)(ws + 58720256);         // 16 MiB
  unsigned short* y_ws = (unsigned short*)(ws + 75497472);         // 16 MiB

  k_prep<<<12288, 256, 0, stream>>>(x, x_bf, Wqkv, wqkvT, Wproj, wprojT);
  k_gemm<0><<<dim3(24, 64), 256, 0, stream>>>(x_bf, wqkvT, nullptr, q_ws, k_ws, v_ws, 8192, 3072);
  k_attn<<<1024, 256, 0, stream>>>(q_ws, k_ws, v_ws, y_ws);
  k_gemm<1><<<dim3(8, 64), 256, 0, stream>>>(y_ws, wprojT, out, nullptr, nullptr, nullptr, 8192, 1024);
}